// Round 7
// baseline (251.326 us; speedup 1.0000x reference)
//
#include <hip/hip_runtime.h>
#include <hip/hip_bf16.h>
#include <math.h>
#include <type_traits>

// ---------------------------------------------------------------------------
// SelfAttention B=4,T=2048,D=1024 fp32 in/out.
// Round 17: 8-phase barrier-paced K-loop (m201 template) on stripe layout.
//   R16 post-mortem: per-CU SERIAL SUM of {MFMA 49k, ds_read 74k, DMA 18k,
//   VALU 14k} = 155k cy = 64.6us == measured 65.8us -> pipes add, not
//   overlap (per-s-step convoy: all waves' reads queue on the LDS FIFO,
//   MFMA idles during drain). Fix = m201's phase pacing:
//   BK=64, 4 phases/tile; phase s = {ds_read frags(ku=s) | issue 1 future
//   quarter -> barrier -> setprio MFMA cluster -> barrier}. Quarter issue
//   schedule: phase 0 of tile t issues q3 of t+1; phases 1-3 issue q0-2 of
//   t+2 -> at tile top 3 quarters (6 GLD) in flight -> counted vmcnt(6),
//   vmcnt(0) only at last tile.
//   WAR safety: phase s (s>=1) overwrites quarter s-1 of the CURRENT buf;
//   all waves' reads of q(s-1) drained (lgkm before their phase-(s-1)
//   MFMAs) and sealed by phase-(s-1) end barrier. Phase-0 write targets the
//   other buf whose readers finished last tile (top barrier).
// Stripe layout (R15/R16 verified): unit u=(r>>5)*(K>>4)+(k>>4), 512 els;
// el p=((r&31)+32*((k>>3)&1))*8+(k&7). GLD16 of a unit: 1KB contiguous
// global src + lane-linear LDS dst = 0-conflict MFMA fragments.
// Geometry: BM=256, BN templ: proj/exp 256 (acc[4][2], wave-tile 128x64),
// div 128 (acc[2][2]) so every grid is a multiple/divisor-clean 256-384.
// Accumulation order identical to R15/R16 -> absmax must stay 0.00048828.
// ---------------------------------------------------------------------------

typedef short shortx8 __attribute__((ext_vector_type(8)));
typedef short shortx4 __attribute__((ext_vector_type(4)));
typedef float floatx16 __attribute__((ext_vector_type(16)));
typedef __attribute__((address_space(3))) void lds_void_t;
typedef __attribute__((address_space(1))) const void gmem_void_t;

#define GLD16(gp, lp) \
    __builtin_amdgcn_global_load_lds((gmem_void_t*)(gp), (lds_void_t*)(lp), 16, 0, 0)

#define MODE_PROJ 0   // z=0,1: C=bf16(A B^T) striped;  z=2: Vt striped
#define MODE_EXP  1   // C = bf16(exp(alpha A B^T)) striped, rowsum += exp
#define MODE_DIV  2   // C = fp32(A B^T) / rowsum[row], row-major

template <int MODE, int BN>
__global__ __launch_bounds__(512, 2) void mfma_gemm_abt(
    const __hip_bfloat16* __restrict__ A, const __hip_bfloat16* __restrict__ B,
    void* __restrict__ Cv, float* __restrict__ rowsum,
    __hip_bfloat16* __restrict__ Vt,
    int M, int N, int K, long sA, long sB, long sC, float alpha)
{
    constexpr int MI  = (BN == 256) ? 4 : 2;      // A-frags per wave
    constexpr int BUF = 16384 + (BN == 256 ? 16384 : 8192);  // els per buffer
    __shared__ __hip_bfloat16 lds[2 * BUF];       // 128KB / 96KB

    using CT = std::conditional_t<MODE == MODE_DIV, float, __hip_bfloat16>;

    const int z = blockIdx.z;
    A += (long)z * sA;
    B += (long)z * sB;
    CT* C = (CT*)Cv + (long)z * sC;

    const int t     = threadIdx.x;          // 0..511
    const int wave  = t >> 6;               // 0..7
    const int lane  = t & 63;
    const int m0    = blockIdx.x * 256;
    const int n0    = blockIdx.y * BN;
    const int wm    = (BN == 256) ? (wave >> 2) * 128 : (wave >> 1) * 64;
    const int wn    = (BN == 256) ? (wave & 3) * 64   : (wave & 1) * 64;
    const int lrow  = lane & 31;            // col of C
    const int lhalf = lane >> 5;            // +4 rows in C

    // staging sources: wave w owns A rows m0+32w.. / B cols n0+32w..
    const long KU   = (long)(K >> 4);
    const long aSrc = (long)((m0 >> 5) + wave) * KU * 512 + lane * 8;
    const long bSrc = (long)((n0 >> 5) + wave) * KU * 512 + lane * 8;
    const int  dA   = wave * 2048;          // LDS A slots (w*4+q)*512
    const int  dB   = 16384 + wave * 2048;  // LDS B slots

    // fragment read bases: A local rg = wmBase+i, B local rg = wnBase+j
    const int raB = ((BN == 256) ? (wave >> 2) * 8192 : (wave >> 1) * 4096)
                    + lane * 8;                          // + i*2048 + s*512
    const int rbB = 16384
                    + ((BN == 256) ? (wave & 3) * 4096 : (wave & 1) * 4096)
                    + lane * 8;                          // + j*2048 + s*512

    // BN=128: only waves 0..3 stage B (4 rgroups)
#define STAGE_Q(bo_, tau_, q_) do {                                            \
        GLD16(A + aSrc + (long)(4 * (tau_) + (q_)) * 512,                      \
              lds + (bo_) + dA + (q_) * 512);                                  \
        if (BN == 256 || wave < 4)                                             \
            GLD16(B + bSrc + (long)(4 * (tau_) + (q_)) * 512,                  \
                  lds + (bo_) + dB + (q_) * 512);                              \
    } while (0)

    floatx16 acc[MI][2] = {};
    const int KT = K >> 6;                  // BK=64; KT = 16 or 32

    // prologue: all of tile 0, quarters 0..2 of tile 1
    #pragma unroll
    for (int q = 0; q < 4; ++q) STAGE_Q(0, 0, q);
    #pragma unroll
    for (int q = 0; q < 3; ++q) STAGE_Q(BUF, 1, q);

    for (int kt = 0; kt < KT; ++kt) {
        const int bo = (kt & 1) ? BUF : 0;
        const int bn = bo ^ BUF;
        // counted wait: tile kt landed; 3 quarters (6/3 GLD) stay in flight
        if (kt + 1 < KT) {
            if (BN == 256 || wave < 4)
                asm volatile("s_waitcnt vmcnt(6)" ::: "memory");
            else
                asm volatile("s_waitcnt vmcnt(3)" ::: "memory");
        } else {
            asm volatile("s_waitcnt vmcnt(0)" ::: "memory");
        }
        __builtin_amdgcn_s_barrier();          // publish tile kt
        __builtin_amdgcn_sched_barrier(0);

        const __hip_bfloat16* Ls = lds + bo;

        #pragma unroll
        for (int s = 0; s < 4; ++s) {
            // --- ds_read fragments for ku=s
            shortx8 a[MI], b[2];
            #pragma unroll
            for (int i = 0; i < MI; ++i)
                a[i] = *(const shortx8*)(Ls + raB + i * 2048 + s * 512);
            #pragma unroll
            for (int j = 0; j < 2; ++j)
                b[j] = *(const shortx8*)(Ls + rbB + j * 2048 + s * 512);
            // --- issue one future quarter (schedule in header comment)
            if (s == 0) {
                if (kt + 1 < KT) STAGE_Q(bn, kt + 1, 3);
            } else {
                if (kt + 2 < KT) STAGE_Q(bo, kt + 2, s - 1);
            }
            __builtin_amdgcn_sched_barrier(0); // pin reads+issues above
            __builtin_amdgcn_s_barrier();      // pacing barrier
            __builtin_amdgcn_sched_barrier(0); // no MFMA hoist above barrier
            __builtin_amdgcn_s_setprio(1);
            #pragma unroll
            for (int i = 0; i < MI; ++i)
                #pragma unroll
                for (int j = 0; j < 2; ++j)
                    acc[i][j] = __builtin_amdgcn_mfma_f32_32x32x16_bf16(
                        a[i], b[j], acc[i][j], 0, 0, 0);
            __builtin_amdgcn_s_setprio(0);
            __builtin_amdgcn_s_barrier();      // seal phase (WAR safety)
        }
    }
#undef STAGE_Q

    // stripe store index for C striped with k-dim = N
    auto sidx = [&](int row, int col) -> long {
        return ((long)(row >> 5) * (N >> 4) + (col >> 4)) * 512
             + ((row & 31) + 32 * ((col >> 3) & 1)) * 8 + (col & 7);
    };

    // C/D layout (verified m74/m101): col = lane&31,
    // row = (reg&3) + 8*(reg>>2) + 4*(lane>>5),  reg in [0,16)
    if constexpr (MODE == MODE_PROJ) {
        if (z == 2) {
            // V -> Vt striped over (rows=d 1024, k=t 2048)
            const int bz   = m0 >> 11;          // batch = row / T
            const long bo2 = (long)bz * N * 2048;
            #pragma unroll
            for (int i = 0; i < MI; ++i)
                #pragma unroll
                for (int j = 0; j < 2; ++j)
                    #pragma unroll
                    for (int g = 0; g < 4; ++g) {
                        const int t0 = (m0 + wm + 32 * i + g * 8 + 4 * lhalf) & 2047;
                        const int d  = n0 + wn + 32 * j + lrow;
                        shortx4 pk;
                        #pragma unroll
                        for (int r = 0; r < 4; ++r) {
                            __hip_bfloat16 hb = __float2bfloat16(acc[i][j][4 * g + r]);
                            pk[r] = *(short*)&hb;
                        }
                        const long idx = bo2
                            + ((long)(d >> 5) * 128 + (t0 >> 4)) * 512
                            + ((d & 31) + 32 * ((t0 >> 3) & 1)) * 8 + (t0 & 7);
                        *(shortx4*)(Vt + idx) = pk;   // 4 consecutive t els
                    }
        } else {
            #pragma unroll
            for (int i = 0; i < MI; ++i)
                #pragma unroll
                for (int j = 0; j < 2; ++j)
                    #pragma unroll
                    for (int g = 0; g < 4; ++g)
                        #pragma unroll
                        for (int r = 0; r < 4; ++r) {
                            const int row = m0 + wm + 32 * i + g * 8 + 4 * lhalf + r;
                            const int col = n0 + wn + 32 * j + lrow;
                            C[sidx(row, col)] = __float2bfloat16(acc[i][j][4 * g + r]);
                        }
        }
    } else if constexpr (MODE == MODE_EXP) {
        #pragma unroll
        for (int i = 0; i < MI; ++i) {
            float rs[16];
            #pragma unroll
            for (int reg = 0; reg < 16; ++reg) rs[reg] = 0.0f;
            #pragma unroll
            for (int j = 0; j < 2; ++j)
                #pragma unroll
                for (int g = 0; g < 4; ++g)
                    #pragma unroll
                    for (int r = 0; r < 4; ++r) {
                        const int row = m0 + wm + 32 * i + g * 8 + 4 * lhalf + r;
                        const int col = n0 + wn + 32 * j + lrow;
                        const float e = __expf(acc[i][j][4 * g + r] * alpha);
                        rs[4 * g + r] += e;
                        C[sidx(row, col)] = __float2bfloat16(e);
                    }
            #pragma unroll
            for (int reg = 0; reg < 16; ++reg) {
                float v = rs[reg];
                v += __shfl_xor(v, 1);
                v += __shfl_xor(v, 2);
                v += __shfl_xor(v, 4);
                v += __shfl_xor(v, 8);
                v += __shfl_xor(v, 16);
                if (lrow == 0) {
                    const long row = m0 + wm + 32 * i + (reg >> 2) * 8 + 4 * lhalf + (reg & 3);
                    atomicAdd(&rowsum[(long)z * M + row], v);
                }
            }
        }
    } else {  // MODE_DIV: out row-major fp32
        #pragma unroll
        for (int i = 0; i < MI; ++i) {
            float inv[16];
            #pragma unroll
            for (int g = 0; g < 4; ++g)
                #pragma unroll
                for (int r = 0; r < 4; ++r) {
                    const long row = m0 + wm + 32 * i + g * 8 + 4 * lhalf + r;
                    inv[4 * g + r] = 1.0f / rowsum[(long)z * M + row];
                }
            #pragma unroll
            for (int j = 0; j < 2; ++j)
                #pragma unroll
                for (int g = 0; g < 4; ++g)
                    #pragma unroll
                    for (int r = 0; r < 4; ++r) {
                        const long row = m0 + wm + 32 * i + g * 8 + 4 * lhalf + r;
                        const long col = n0 + wn + 32 * j + lrow;
                        C[row * N + col] = acc[i][j][4 * g + r] * inv[4 * g + r];
                    }
        }
    }
}

// prep: cast x / Wq|Wk|Wv fp32->bf16 into stripe layout via LDS transpose.
// Block = one 32-row group x K=1024: coalesced float4 reads -> striped LDS
// image (64KB) -> 64KB CONTIGUOUS global write. Blocks 0..255: xb;
// 256..351: Wb. Blocks 0..31 also zero rowsum.
__global__ __launch_bounds__(256) void prep(
    const float* __restrict__ x,
    const float* __restrict__ W0, const float* __restrict__ W1,
    const float* __restrict__ W2,
    __hip_bfloat16* __restrict__ xb, __hip_bfloat16* __restrict__ Wb,
    float* __restrict__ rowsum)
{
    __shared__ __hip_bfloat16 sb[32768];    // 64KB striped image

    const int b  = blockIdx.x;
    const int tt = threadIdx.x;             // 0..255

    if (b < 32) {
        float4 zz; zz.x = zz.y = zz.z = zz.w = 0.0f;
        ((float4*)rowsum)[b * 256 + tt] = zz;
    }

    const float* src;
    __hip_bfloat16* dst;
    if (b < 256) {
        src = x + (long)b * 32 * 1024;
        dst = xb + (long)b * 32768;
    } else {
        const int w  = (b - 256) >> 5;
        const int rg = (b - 256) & 31;
        src = ((w == 0) ? W0 : (w == 1) ? W1 : W2) + (long)rg * 32 * 1024;
        dst = Wb + (long)w * 1048576 + (long)rg * 32768;
    }

    #pragma unroll
    for (int it = 0; it < 32; ++it) {
        const int idx4 = it * 256 + tt;         // float4 index in row-major
        const float4 f = ((const float4*)src)[idx4];
        const int row = idx4 >> 8;              // 256 float4 per row
        const int k0  = (idx4 & 255) << 2;
        const int p   = ((row & 31) + 32 * ((k0 >> 3) & 1)) * 8 + (k0 & 7);
        shortx4 pk;
        __hip_bfloat16 h0 = __float2bfloat16(f.x); pk[0] = *(short*)&h0;
        __hip_bfloat16 h1 = __float2bfloat16(f.y); pk[1] = *(short*)&h1;
        __hip_bfloat16 h2 = __float2bfloat16(f.z); pk[2] = *(short*)&h2;
        __hip_bfloat16 h3 = __float2bfloat16(f.w); pk[3] = *(short*)&h3;
        *(shortx4*)(sb + (k0 >> 4) * 512 + p) = pk;
    }
    __syncthreads();

    #pragma unroll
    for (int ot = 0; ot < 16; ++ot) {
        const int off = ot * 2048 + tt * 8;
        *(shortx8*)(dst + off) = *(const shortx8*)(sb + off);
    }
}

extern "C" void kernel_launch(void* const* d_in, const int* in_sizes, int n_in,
                              void* d_out, int out_size, void* d_ws, size_t ws_size,
                              hipStream_t stream)
{
    constexpr int  Bb = 4, T = 2048, D = 1024;
    constexpr int  M  = Bb * T;                 // 8192
    constexpr long TD = (long)T * D;            // 2,097,152
    constexpr long TT = (long)T * T;            // 4,194,304
    constexpr long MD = (long)M * D;            // 8,388,608

    const float* x  = (const float*)d_in[0];
    const float* Wq = (const float*)d_in[1];
    const float* Wk = (const float*)d_in[2];
    const float* Wv = (const float*)d_in[3];
    float* out = (float*)d_out;

    // workspace: Q|K|Vt (bf16 16MB each) | P (bf16 33.6MB) | xb (16MB)
    //            | Wb (6MB) | rowsum (32KB)   -> ~104 MB  (all striped)
    __hip_bfloat16* Q  = (__hip_bfloat16*)d_ws;
    __hip_bfloat16* Kb = Q + MD;
    __hip_bfloat16* Vt = Kb + MD;
    __hip_bfloat16* P  = Vt + MD;
    __hip_bfloat16* xb = P + (long)Bb * TT;
    __hip_bfloat16* Wb = xb + MD;
    float*     rowsum  = (float*)(Wb + 3L * D * D);

    prep<<<dim3(352), dim3(256), 0, stream>>>(x, Wq, Wk, Wv, xb, Wb, rowsum);

    dim3 blk(512);

    // projections: z=0 -> Q, z=1 -> K, z=2 -> Vt (striped)
    mfma_gemm_abt<MODE_PROJ, 256><<<dim3(M / 256, D / 256, 3), blk, 0, stream>>>(
        xb, Wb, Q, nullptr, Vt, M, D, D, 0, (long)D * D, MD, 1.0f);

    // P = exp(Q K^T / 32) bf16 striped, rowsum via atomics
    mfma_gemm_abt<MODE_EXP, 256><<<dim3(T / 256, T / 256, Bb), blk, 0, stream>>>(
        Q, Kb, P, rowsum, nullptr, T, T, D, TD, TD, TT, 0.03125f);

    // out = (P @ Vt^T) / rowsum[row]  (row-major fp32 output)
    mfma_gemm_abt<MODE_DIV, 128><<<dim3(T / 256, D / 128, Bb), blk, 0, stream>>>(
        P, Vt, out, rowsum, nullptr, T, D, T, TT, TD, TD, 1.0f);

    (void)in_sizes; (void)n_in; (void)out_size; (void)ws_size;
}

// Round 8
// 249.872 us; speedup vs baseline: 1.0058x; 1.0058x over previous
//
#include <hip/hip_runtime.h>
#include <hip/hip_bf16.h>
#include <math.h>
#include <type_traits>

// ---------------------------------------------------------------------------
// SelfAttention B=4,T=2048,D=1024 fp32 in/out.
// Round 18: cut LDS-port traffic per MFMA (the binding constraint).
//   R15-R17 post-mortem: every schedule variant (drift / 3-ring counted
//   vmcnt / 8-phase pacing) landed 65-75us at ~30% MfmaUtil. Model fit:
//   LDS pipe work per block-tile (64 b128 reads + 24 DMA writes ~ 1400-1900
//   cy for 2 co-resident blocks) == measured wall (2x685cy) -> the shared
//   LDS data path is saturated; scheduling cannot help.
//   Fix: reads:MFMA 1:1 -> 0.75:1 via wave-tile 128x64 (acc[4][2], 6 frag
//   reads per 8 MFMAs). 4-wave blocks (256 thr) keep block-tile 256x128 so
//   grids stay balanced (proj 768=3/CU, exp 512=2/CU, div 256=1/CU).
//   Loop = R15's proven drift structure (stage(kt+1) at top, one barrier +
//   late vmcnt(0) per tile); R17's pacing barriers removed.
// Stripe layout (R15+, verified 0-conflict): unit u=(r>>5)*(K>>4)+(k>>4),
// 512 els; el p=((r&31)+32*((k>>3)&1))*8+(k&7). GLD16 of one unit: 1KB
// contiguous global src + lane-linear LDS dst = exact MFMA fragments.
// LDS buffer (BK=32): A 8 rgroups x 2 kunits at (rg*2+hp)*512 (16KB),
// B 4 rgroups at 8192+(rg*2+hp)*512 (8KB); 24KB/buf, dbuf 48KB.
// Staging: wave w owns A rgroups 2w,2w+1 and B rgroup w (6 GLD/tile/wave).
// Accumulation order identical to R15-R17 -> absmax must stay 0.00048828.
// ---------------------------------------------------------------------------

typedef short shortx8 __attribute__((ext_vector_type(8)));
typedef short shortx4 __attribute__((ext_vector_type(4)));
typedef float floatx16 __attribute__((ext_vector_type(16)));
typedef __attribute__((address_space(3))) void lds_void_t;
typedef __attribute__((address_space(1))) const void gmem_void_t;

#define GLD16(gp, lp) \
    __builtin_amdgcn_global_load_lds((gmem_void_t*)(gp), (lds_void_t*)(lp), 16, 0, 0)

#define MODE_PROJ 0   // z=0,1: C=bf16(A B^T) striped;  z=2: Vt striped
#define MODE_EXP  1   // C = bf16(exp(alpha A B^T)) striped, rowsum += exp
#define MODE_DIV  2   // C = fp32(A B^T) / rowsum[row], row-major

// C[M,N] = f(A[M,K] @ B[N,K]^T). A,B striped (k-dim = K). z-batched.
// 256x128 tile, BK=32, 4 waves: wm=(w>>1)*128, wn=(w&1)*64, acc[4][2].
template <int MODE>
__global__ __launch_bounds__(256, 2) void mfma_gemm_abt(
    const __hip_bfloat16* __restrict__ A, const __hip_bfloat16* __restrict__ B,
    void* __restrict__ Cv, float* __restrict__ rowsum,
    __hip_bfloat16* __restrict__ Vt,
    int M, int N, int K, long sA, long sB, long sC, float alpha)
{
    __shared__ __hip_bfloat16 lds[2 * 12288];   // 48KB

    using CT = std::conditional_t<MODE == MODE_DIV, float, __hip_bfloat16>;

    const int z = blockIdx.z;
    A += (long)z * sA;
    B += (long)z * sB;
    CT* C = (CT*)Cv + (long)z * sC;

    const int t     = threadIdx.x;          // 0..255
    const int wave  = t >> 6;               // 0..3
    const int lane  = t & 63;
    const int m0    = blockIdx.x * 256;
    const int n0    = blockIdx.y * 128;
    const int wm    = (wave >> 1) * 128;    // 0,128
    const int wn    = (wave & 1) * 64;      // 0,64
    const int lrow  = lane & 31;            // col of C
    const int lhalf = lane >> 5;            // +4 rows in C

    // staging: wave w owns A rgroups 2w,2w+1 and B rgroup w.
    const long KU   = (long)(K >> 4);       // k-units per row-group
    const long aSrc = (long)((m0 >> 5) + 2 * wave) * KU * 512 + lane * 8;
    const long bSrc = (long)((n0 >> 5) + wave) * KU * 512 + lane * 8;
    const int  dA   = wave * 2048;          // A slots (4w+q)*512 / +1024
    const int  dB   = 8192 + wave * 1024;   // B slots

    // fragment read bases (R13/R15-verified lane-linear, 0-conflict):
    // A frag i: ((w>>1)*4+i)*1024 + s*512; B frag j: (w&1)*2048 + j*1024 + s*512
    const int raB = (wave >> 1) * 4096 + lane * 8;
    const int rbB = 8192 + (wave & 1) * 2048 + lane * 8;

#define STAGE(bo_, kt_) do {                                                  \
        _Pragma("unroll")                                                     \
        for (int q = 0; q < 2; ++q) {                                         \
            GLD16(A + aSrc + (long)(2 * (kt_) + q) * 512,                     \
                  lds + (bo_) + dA + q * 512);                                \
            GLD16(A + aSrc + (KU + 2 * (kt_) + q) * 512,                      \
                  lds + (bo_) + dA + 1024 + q * 512);                         \
            GLD16(B + bSrc + (long)(2 * (kt_) + q) * 512,                     \
                  lds + (bo_) + dB + q * 512);                                \
        }                                                                     \
    } while (0)

    floatx16 acc[4][2] = {};
    const int KT = K >> 5;

    STAGE(0, 0);                                  // prologue: tile 0 -> buf 0
    asm volatile("s_waitcnt vmcnt(0)" ::: "memory");
    __builtin_amdgcn_s_barrier();

    for (int kt = 0; kt < KT; ++kt) {
        if (kt + 1 < KT)                          // issue-early for tile kt+1
            STAGE(((kt + 1) & 1) * 12288, kt + 1);

        const __hip_bfloat16* Ls = lds + (kt & 1) * 12288;

        #pragma unroll
        for (int s = 0; s < 2; ++s) {             // two K=16 steps
            shortx8 a[4], b[2];
            #pragma unroll
            for (int i = 0; i < 4; ++i)
                a[i] = *(const shortx8*)(Ls + raB + i * 1024 + s * 512);
            #pragma unroll
            for (int j = 0; j < 2; ++j)
                b[j] = *(const shortx8*)(Ls + rbB + j * 1024 + s * 512);
            __builtin_amdgcn_s_setprio(1);
            #pragma unroll
            for (int i = 0; i < 4; ++i)
                #pragma unroll
                for (int j = 0; j < 2; ++j)
                    acc[i][j] = __builtin_amdgcn_mfma_f32_32x32x16_bf16(
                        a[i], b[j], acc[i][j], 0, 0, 0);
            __builtin_amdgcn_s_setprio(0);
        }
        // own stage(kt+1) done; all reads of buf^1 retired before barrier
        asm volatile("s_waitcnt vmcnt(0)" ::: "memory");
        __builtin_amdgcn_s_barrier();
    }
#undef STAGE

    // stripe store index for C striped with k-dim = N
    auto sidx = [&](int row, int col) -> long {
        return ((long)(row >> 5) * (N >> 4) + (col >> 4)) * 512
             + ((row & 31) + 32 * ((col >> 3) & 1)) * 8 + (col & 7);
    };

    // C/D layout (verified m74/m101): col = lane&31,
    // row = (reg&3) + 8*(reg>>2) + 4*(lane>>5),  reg in [0,16)
    if constexpr (MODE == MODE_PROJ) {
        if (z == 2) {
            // V -> Vt striped over (rows=d 1024, k=t 2048)
            const int bz   = m0 >> 11;          // batch = row / T
            const long bo2 = (long)bz * N * 2048;
            #pragma unroll
            for (int i = 0; i < 4; ++i)
                #pragma unroll
                for (int j = 0; j < 2; ++j)
                    #pragma unroll
                    for (int g = 0; g < 4; ++g) {
                        const int t0 = (m0 + wm + 32 * i + g * 8 + 4 * lhalf) & 2047;
                        const int d  = n0 + wn + 32 * j + lrow;
                        shortx4 pk;
                        #pragma unroll
                        for (int r = 0; r < 4; ++r) {
                            __hip_bfloat16 hb = __float2bfloat16(acc[i][j][4 * g + r]);
                            pk[r] = *(short*)&hb;
                        }
                        const long idx = bo2
                            + ((long)(d >> 5) * 128 + (t0 >> 4)) * 512
                            + ((d & 31) + 32 * ((t0 >> 3) & 1)) * 8 + (t0 & 7);
                        *(shortx4*)(Vt + idx) = pk;   // 4 consecutive t els
                    }
        } else {
            #pragma unroll
            for (int i = 0; i < 4; ++i)
                #pragma unroll
                for (int j = 0; j < 2; ++j)
                    #pragma unroll
                    for (int g = 0; g < 4; ++g)
                        #pragma unroll
                        for (int r = 0; r < 4; ++r) {
                            const int row = m0 + wm + 32 * i + g * 8 + 4 * lhalf + r;
                            const int col = n0 + wn + 32 * j + lrow;
                            C[sidx(row, col)] = __float2bfloat16(acc[i][j][4 * g + r]);
                        }
        }
    } else if constexpr (MODE == MODE_EXP) {
        #pragma unroll
        for (int i = 0; i < 4; ++i) {
            float rs[16];
            #pragma unroll
            for (int reg = 0; reg < 16; ++reg) rs[reg] = 0.0f;
            #pragma unroll
            for (int j = 0; j < 2; ++j)
                #pragma unroll
                for (int g = 0; g < 4; ++g)
                    #pragma unroll
                    for (int r = 0; r < 4; ++r) {
                        const int row = m0 + wm + 32 * i + g * 8 + 4 * lhalf + r;
                        const int col = n0 + wn + 32 * j + lrow;
                        const float e = __expf(acc[i][j][4 * g + r] * alpha);
                        rs[4 * g + r] += e;
                        C[sidx(row, col)] = __float2bfloat16(e);
                    }
            #pragma unroll
            for (int reg = 0; reg < 16; ++reg) {
                float v = rs[reg];
                v += __shfl_xor(v, 1);
                v += __shfl_xor(v, 2);
                v += __shfl_xor(v, 4);
                v += __shfl_xor(v, 8);
                v += __shfl_xor(v, 16);
                if (lrow == 0) {
                    const long row = m0 + wm + 32 * i + (reg >> 2) * 8 + 4 * lhalf + (reg & 3);
                    atomicAdd(&rowsum[(long)z * M + row], v);
                }
            }
        }
    } else {  // MODE_DIV: out row-major fp32
        #pragma unroll
        for (int i = 0; i < 4; ++i) {
            float inv[16];
            #pragma unroll
            for (int g = 0; g < 4; ++g)
                #pragma unroll
                for (int r = 0; r < 4; ++r) {
                    const long row = m0 + wm + 32 * i + g * 8 + 4 * lhalf + r;
                    inv[4 * g + r] = 1.0f / rowsum[(long)z * M + row];
                }
            #pragma unroll
            for (int j = 0; j < 2; ++j)
                #pragma unroll
                for (int g = 0; g < 4; ++g)
                    #pragma unroll
                    for (int r = 0; r < 4; ++r) {
                        const long row = m0 + wm + 32 * i + g * 8 + 4 * lhalf + r;
                        const long col = n0 + wn + 32 * j + lrow;
                        C[row * N + col] = acc[i][j][4 * g + r] * inv[4 * g + r];
                    }
        }
    }
}

// prep: cast x / Wq|Wk|Wv fp32->bf16 into stripe layout via LDS transpose.
// Block = one 32-row group x K=1024: coalesced float4 reads -> striped LDS
// image (64KB) -> 64KB CONTIGUOUS global write. Blocks 0..255: xb;
// 256..351: Wb. Blocks 0..31 also zero rowsum.
__global__ __launch_bounds__(256) void prep(
    const float* __restrict__ x,
    const float* __restrict__ W0, const float* __restrict__ W1,
    const float* __restrict__ W2,
    __hip_bfloat16* __restrict__ xb, __hip_bfloat16* __restrict__ Wb,
    float* __restrict__ rowsum)
{
    __shared__ __hip_bfloat16 sb[32768];    // 64KB striped image

    const int b  = blockIdx.x;
    const int tt = threadIdx.x;             // 0..255

    if (b < 32) {
        float4 zz; zz.x = zz.y = zz.z = zz.w = 0.0f;
        ((float4*)rowsum)[b * 256 + tt] = zz;
    }

    const float* src;
    __hip_bfloat16* dst;
    if (b < 256) {
        src = x + (long)b * 32 * 1024;
        dst = xb + (long)b * 32768;
    } else {
        const int w  = (b - 256) >> 5;
        const int rg = (b - 256) & 31;
        src = ((w == 0) ? W0 : (w == 1) ? W1 : W2) + (long)rg * 32 * 1024;
        dst = Wb + (long)w * 1048576 + (long)rg * 32768;
    }

    #pragma unroll
    for (int it = 0; it < 32; ++it) {
        const int idx4 = it * 256 + tt;         // float4 index in row-major
        const float4 f = ((const float4*)src)[idx4];
        const int row = idx4 >> 8;              // 256 float4 per row
        const int k0  = (idx4 & 255) << 2;
        const int p   = ((row & 31) + 32 * ((k0 >> 3) & 1)) * 8 + (k0 & 7);
        shortx4 pk;
        __hip_bfloat16 h0 = __float2bfloat16(f.x); pk[0] = *(short*)&h0;
        __hip_bfloat16 h1 = __float2bfloat16(f.y); pk[1] = *(short*)&h1;
        __hip_bfloat16 h2 = __float2bfloat16(f.z); pk[2] = *(short*)&h2;
        __hip_bfloat16 h3 = __float2bfloat16(f.w); pk[3] = *(short*)&h3;
        *(shortx4*)(sb + (k0 >> 4) * 512 + p) = pk;
    }
    __syncthreads();

    #pragma unroll
    for (int ot = 0; ot < 16; ++ot) {
        const int off = ot * 2048 + tt * 8;
        *(shortx8*)(dst + off) = *(const shortx8*)(sb + off);
    }
}

extern "C" void kernel_launch(void* const* d_in, const int* in_sizes, int n_in,
                              void* d_out, int out_size, void* d_ws, size_t ws_size,
                              hipStream_t stream)
{
    constexpr int  Bb = 4, T = 2048, D = 1024;
    constexpr int  M  = Bb * T;                 // 8192
    constexpr long TD = (long)T * D;            // 2,097,152
    constexpr long TT = (long)T * T;            // 4,194,304
    constexpr long MD = (long)M * D;            // 8,388,608

    const float* x  = (const float*)d_in[0];
    const float* Wq = (const float*)d_in[1];
    const float* Wk = (const float*)d_in[2];
    const float* Wv = (const float*)d_in[3];
    float* out = (float*)d_out;

    // workspace: Q|K|Vt (bf16 16MB each) | P (bf16 33.6MB) | xb (16MB)
    //            | Wb (6MB) | rowsum (32KB)   -> ~104 MB  (all striped)
    __hip_bfloat16* Q  = (__hip_bfloat16*)d_ws;
    __hip_bfloat16* Kb = Q + MD;
    __hip_bfloat16* Vt = Kb + MD;
    __hip_bfloat16* P  = Vt + MD;
    __hip_bfloat16* xb = P + (long)Bb * TT;
    __hip_bfloat16* Wb = xb + MD;
    float*     rowsum  = (float*)(Wb + 3L * D * D);

    prep<<<dim3(352), dim3(256), 0, stream>>>(x, Wq, Wk, Wv, xb, Wb, rowsum);

    dim3 blk(256);

    // projections: z=0 -> Q, z=1 -> K, z=2 -> Vt (striped)
    mfma_gemm_abt<MODE_PROJ><<<dim3(M / 256, D / 128, 3), blk, 0, stream>>>(
        xb, Wb, Q, nullptr, Vt, M, D, D, 0, (long)D * D, MD, 1.0f);

    // P = exp(Q K^T / 32) bf16 striped, rowsum via atomics
    mfma_gemm_abt<MODE_EXP><<<dim3(T / 256, T / 128, Bb), blk, 0, stream>>>(
        Q, Kb, P, rowsum, nullptr, T, T, D, TD, TD, TT, 0.03125f);

    // out = (P @ Vt^T) / rowsum[row]  (row-major fp32 output)
    mfma_gemm_abt<MODE_DIV><<<dim3(T / 256, D / 128, Bb), blk, 0, stream>>>(
        P, Vt, out, rowsum, nullptr, T, D, T, TT, TD, TD, 1.0f);

    (void)in_sizes; (void)n_in; (void)out_size; (void)ws_size;
}